// Round 1
// baseline (2634.100 us; speedup 1.0000x reference)
//
#include <hip/hip_runtime.h>
#include <hip/hip_bf16.h>
#include <math.h>

#define BB   8
#define CC   256
#define HH   128
#define WW   128
#define MID  64
#define NPIX (HH * WW)          // 16384
#define BN_EPS 1e-5f

// Compute bilinear sample coordinates for rotation grid at output pixel (xx, yy).
__device__ __forceinline__ void rot_coords(int xx, int yy, float c, float s,
                                           int& x0, int& y0, float& wx1, float& wy1) {
    float X = -1.0f + (2.0f * (float)xx) / (float)(WW - 1);
    float Y = -1.0f + (2.0f * (float)yy) / (float)(HH - 1);
    float gx = c * X - s * Y;
    float gy = s * X + c * Y;
    float ix = (gx + 1.0f) * 0.5f * (float)(WW - 1);
    float iy = (gy + 1.0f) * 0.5f * (float)(HH - 1);
    float fx = floorf(ix), fy = floorf(iy);
    x0 = (int)fx; y0 = (int)fy;
    wx1 = ix - fx; wy1 = iy - fy;
}

// Kernel 1: rotate x by +angle into bf16 xr, and compute per-plane spatial mean p.
// One block (256 thr) per (b,c) plane.
__global__ void k_rotate(const float* __restrict__ x, const float* __restrict__ angles,
                         int ai, __hip_bfloat16* __restrict__ xr, float* __restrict__ p) {
    int plane = blockIdx.x;                       // b*CC + ch
    float ang = angles[ai];
    float c = cosf(ang), s = sinf(ang);
    const float* img = x + (size_t)plane * NPIX;
    __hip_bfloat16* op = xr + (size_t)plane * NPIX;

    float lsum = 0.0f;
    for (int i = 0; i < NPIX / 256; ++i) {
        int pix = threadIdx.x + (i << 8);
        int yy = pix >> 7, xx = pix & (WW - 1);
        int x0, y0; float wx1, wy1;
        rot_coords(xx, yy, c, s, x0, y0, wx1, wy1);
        int x1 = x0 + 1, y1 = y0 + 1;
        float wx0 = 1.f - wx1, wy0 = 1.f - wy1;
        bool vx0 = (unsigned)x0 < WW, vx1 = (unsigned)x1 < WW;
        bool vy0 = (unsigned)y0 < HH, vy1 = (unsigned)y1 < HH;
        int cx0 = min(max(x0, 0), WW - 1), cx1 = min(max(x1, 0), WW - 1);
        int cy0 = min(max(y0, 0), HH - 1), cy1 = min(max(y1, 0), HH - 1);
        float w00 = (vx0 && vy0) ? wx0 * wy0 : 0.f;
        float w10 = (vx1 && vy0) ? wx1 * wy0 : 0.f;
        float w01 = (vx0 && vy1) ? wx0 * wy1 : 0.f;
        float w11 = (vx1 && vy1) ? wx1 * wy1 : 0.f;
        float v = w00 * img[cy0 * WW + cx0] + w10 * img[cy0 * WW + cx1]
                + w01 * img[cy1 * WW + cx0] + w11 * img[cy1 * WW + cx1];
        op[pix] = __float2bfloat16(v);
        lsum += v;
    }
    // block reduction: 4 waves of 64
    for (int off = 32; off > 0; off >>= 1) lsum += __shfl_down(lsum, off, 64);
    __shared__ float red[4];
    if ((threadIdx.x & 63) == 0) red[threadIdx.x >> 6] = lsum;
    __syncthreads();
    if (threadIdx.x == 0)
        p[plane] = (red[0] + red[1] + red[2] + red[3]) * (1.0f / (float)NPIX);
}

// Kernel 2: tiny MLP: h = relu(BN(p @ w1^T)); ca = sigmoid(h @ w2^T). One block.
__global__ void k_mlp(const float* __restrict__ p, const float* __restrict__ w1,
                      const float* __restrict__ g, const float* __restrict__ be,
                      const float* __restrict__ mu, const float* __restrict__ var,
                      const float* __restrict__ w2, float* __restrict__ ca) {
    __shared__ float sp[BB * CC];    // 2048
    __shared__ float sh[BB * MID];   // 512
    int t = threadIdx.x;
    for (int i = t; i < BB * CC; i += 256) sp[i] = p[i];
    __syncthreads();
    for (int i = t; i < BB * MID; i += 256) {
        int b = i >> 6, m = i & (MID - 1);
        float acc = 0.f;
        for (int k = 0; k < CC; ++k) acc += sp[b * CC + k] * w1[m * CC + k];
        acc = (acc - mu[m]) * rsqrtf(var[m] + BN_EPS) * g[m] + be[m];
        sh[i] = fmaxf(acc, 0.f);
    }
    __syncthreads();
    for (int i = t; i < BB * CC; i += 256) {
        int b = i >> 8, ch = i & (CC - 1);
        float acc = 0.f;
        for (int k = 0; k < MID; ++k) acc += sh[b * MID + k] * w2[ch * MID + k];
        ca[i] = 1.f / (1.f + expf(-acc));
    }
}

// Kernel 3: per-pixel channel avg & max of fca = xr * ca.
// grid = BB*64 blocks, 256 threads; each thread owns one pixel, loops channels.
__global__ void k_chanstat(const __hip_bfloat16* __restrict__ xr, const float* __restrict__ ca,
                           float* __restrict__ avg, float* __restrict__ mx) {
    int b = blockIdx.x >> 6;
    int pix = ((blockIdx.x & 63) << 8) + threadIdx.x;
    size_t base = (size_t)b * CC * NPIX + pix;
    const float* cab = ca + b * CC;
    float s = 0.f, m = -INFINITY;
    for (int ch = 0; ch < CC; ++ch) {
        float v = __bfloat162float(xr[base + (size_t)ch * NPIX]) * cab[ch];
        s += v;
        m = fmaxf(m, v);
    }
    avg[b * NPIX + pix] = s * (1.0f / (float)CC);
    mx[b * NPIX + pix] = m;
}

// Kernel 4: 7x7 conv (2 in-ch -> 1), pad 3, then sigmoid -> sa.
__global__ void k_conv(const float* __restrict__ avg, const float* __restrict__ mx,
                       const float* __restrict__ w_sp, float* __restrict__ sa) {
    __shared__ float w[98];
    int t = threadIdx.x;
    if (t < 98) w[t] = w_sp[t];
    __syncthreads();
    int b = blockIdx.x >> 6;
    int pix = ((blockIdx.x & 63) << 8) + t;
    int yy = pix >> 7, xx = pix & (WW - 1);
    const float* a0 = avg + b * NPIX;
    const float* a1 = mx + b * NPIX;
    float acc = 0.f;
    for (int ky = 0; ky < 7; ++ky) {
        int ys = yy + ky - 3;
        if ((unsigned)ys >= HH) continue;
        for (int kx = 0; kx < 7; ++kx) {
            int xs = xx + kx - 3;
            if ((unsigned)xs >= WW) continue;
            acc += a0[ys * WW + xs] * w[ky * 7 + kx] + a1[ys * WW + xs] * w[49 + ky * 7 + kx];
        }
    }
    sa[b * NPIX + pix] = 1.f / (1.f + expf(-acc));
}

// Kernel 5: inverse rotate fatt = xr*ca*sa by -angle, scale by 1/4, accumulate into out.
__global__ void k_invrot(const __hip_bfloat16* __restrict__ xr, const float* __restrict__ ca,
                         const float* __restrict__ sa, const float* __restrict__ angles,
                         int ai, int first, float* __restrict__ out) {
    int plane = blockIdx.x;
    int b = plane >> 8;
    float ang = angles[ai];
    float c = cosf(ang), s = -sinf(ang);       // inverse rotation grid
    float scale = ca[plane] * 0.25f;
    const __hip_bfloat16* xp = xr + (size_t)plane * NPIX;
    const float* sp = sa + b * NPIX;
    float* op = out + (size_t)plane * NPIX;

    for (int i = 0; i < NPIX / 256; ++i) {
        int pix = threadIdx.x + (i << 8);
        int yy = pix >> 7, xx = pix & (WW - 1);
        int x0, y0; float wx1, wy1;
        rot_coords(xx, yy, c, s, x0, y0, wx1, wy1);
        int x1 = x0 + 1, y1 = y0 + 1;
        float wx0 = 1.f - wx1, wy0 = 1.f - wy1;
        bool vx0 = (unsigned)x0 < WW, vx1 = (unsigned)x1 < WW;
        bool vy0 = (unsigned)y0 < HH, vy1 = (unsigned)y1 < HH;
        int cx0 = min(max(x0, 0), WW - 1), cx1 = min(max(x1, 0), WW - 1);
        int cy0 = min(max(y0, 0), HH - 1), cy1 = min(max(y1, 0), HH - 1);
        int i00 = cy0 * WW + cx0, i10 = cy0 * WW + cx1;
        int i01 = cy1 * WW + cx0, i11 = cy1 * WW + cx1;
        float w00 = (vx0 && vy0) ? wx0 * wy0 : 0.f;
        float w10 = (vx1 && vy0) ? wx1 * wy0 : 0.f;
        float w01 = (vx0 && vy1) ? wx0 * wy1 : 0.f;
        float w11 = (vx1 && vy1) ? wx1 * wy1 : 0.f;
        float v = w00 * __bfloat162float(xp[i00]) * sp[i00]
                + w10 * __bfloat162float(xp[i10]) * sp[i10]
                + w01 * __bfloat162float(xp[i01]) * sp[i01]
                + w11 * __bfloat162float(xp[i11]) * sp[i11];
        float o = v * scale;
        if (first) op[pix] = o;
        else       op[pix] += o;
    }
}

extern "C" void kernel_launch(void* const* d_in, const int* in_sizes, int n_in,
                              void* d_out, int out_size, void* d_ws, size_t ws_size,
                              hipStream_t stream) {
    const float* x      = (const float*)d_in[0];
    const float* angles = (const float*)d_in[1];
    const float* w1     = (const float*)d_in[2];
    const float* gmm    = (const float*)d_in[3];
    const float* bet    = (const float*)d_in[4];
    const float* mu     = (const float*)d_in[5];
    const float* var    = (const float*)d_in[6];
    const float* w2     = (const float*)d_in[7];
    const float* wsp    = (const float*)d_in[8];
    float* out = (float*)d_out;

    char* ws = (char*)d_ws;
    __hip_bfloat16* xr = (__hip_bfloat16*)ws;                 // 8*256*128*128 * 2B = 64 MiB
    float* p   = (float*)(ws + (size_t)BB * CC * NPIX * 2);
    float* ca  = p + BB * CC;
    float* avg = ca + BB * CC;
    float* mx  = avg + BB * NPIX;
    float* sa  = mx + BB * NPIX;

    for (int ai = 0; ai < 4; ++ai) {
        k_rotate  <<<BB * CC, 256, 0, stream>>>(x, angles, ai, xr, p);
        k_mlp     <<<1, 256, 0, stream>>>(p, w1, gmm, bet, mu, var, w2, ca);
        k_chanstat<<<BB * 64, 256, 0, stream>>>(xr, ca, avg, mx);
        k_conv    <<<BB * 64, 256, 0, stream>>>(avg, mx, wsp, sa);
        k_invrot  <<<BB * CC, 256, 0, stream>>>(xr, ca, sa, angles, ai, ai == 0, out);
    }
}

// Round 2
// 1704.101 us; speedup vs baseline: 1.5457x; 1.5457x over previous
//
#include <hip/hip_runtime.h>
#include <hip/hip_bf16.h>
#include <math.h>

#define BB   8
#define CC   256
#define HH   128
#define WW   128
#define MID  64
#define NPIX (HH * WW)          // 16384
#define BN_EPS 1e-5f

// LDS staging pitch/rows for the 32x32-output-tile inverse-rotate kernel.
// Max input bbox span for a 31-px tile under any rotation: 31*sqrt(2)+3 < 48.
#define TPITCH 56
#define TROWS  56

// Compute bilinear sample coordinates for rotation grid at output pixel (xx, yy).
__device__ __forceinline__ void rot_coords(int xx, int yy, float c, float s,
                                           int& x0, int& y0, float& wx1, float& wy1) {
    float X = -1.0f + (2.0f * (float)xx) / (float)(WW - 1);
    float Y = -1.0f + (2.0f * (float)yy) / (float)(HH - 1);
    float gx = c * X - s * Y;
    float gy = s * X + c * Y;
    float ix = (gx + 1.0f) * 0.5f * (float)(WW - 1);
    float iy = (gy + 1.0f) * 0.5f * (float)(HH - 1);
    float fx = floorf(ix), fy = floorf(iy);
    x0 = (int)fx; y0 = (int)fy;
    wx1 = ix - fx; wy1 = iy - fy;
}

__device__ __forceinline__ void rot_ixiy(float xx, float yy, float c, float s,
                                         float& ix, float& iy) {
    float X = -1.0f + (2.0f * xx) / (float)(WW - 1);
    float Y = -1.0f + (2.0f * yy) / (float)(HH - 1);
    float gx = c * X - s * Y;
    float gy = s * X + c * Y;
    ix = (gx + 1.0f) * 0.5f * (float)(WW - 1);
    iy = (gy + 1.0f) * 0.5f * (float)(HH - 1);
}

// Kernel 1: rotate x by +angle into bf16 xr, and compute per-plane spatial mean p.
// One block (256 thr) per (b,c) plane.
__global__ void k_rotate(const float* __restrict__ x, const float* __restrict__ angles,
                         int ai, __hip_bfloat16* __restrict__ xr, float* __restrict__ p) {
    int plane = blockIdx.x;                       // b*CC + ch
    float ang = angles[ai];
    float c = cosf(ang), s = sinf(ang);
    const float* img = x + (size_t)plane * NPIX;
    __hip_bfloat16* op = xr + (size_t)plane * NPIX;

    float lsum = 0.0f;
    for (int i = 0; i < NPIX / 256; ++i) {
        int pix = threadIdx.x + (i << 8);
        int yy = pix >> 7, xx = pix & (WW - 1);
        int x0, y0; float wx1, wy1;
        rot_coords(xx, yy, c, s, x0, y0, wx1, wy1);
        int x1 = x0 + 1, y1 = y0 + 1;
        float wx0 = 1.f - wx1, wy0 = 1.f - wy1;
        bool vx0 = (unsigned)x0 < WW, vx1 = (unsigned)x1 < WW;
        bool vy0 = (unsigned)y0 < HH, vy1 = (unsigned)y1 < HH;
        int cx0 = min(max(x0, 0), WW - 1), cx1 = min(max(x1, 0), WW - 1);
        int cy0 = min(max(y0, 0), HH - 1), cy1 = min(max(y1, 0), HH - 1);
        float w00 = (vx0 && vy0) ? wx0 * wy0 : 0.f;
        float w10 = (vx1 && vy0) ? wx1 * wy0 : 0.f;
        float w01 = (vx0 && vy1) ? wx0 * wy1 : 0.f;
        float w11 = (vx1 && vy1) ? wx1 * wy1 : 0.f;
        float v = w00 * img[cy0 * WW + cx0] + w10 * img[cy0 * WW + cx1]
                + w01 * img[cy1 * WW + cx0] + w11 * img[cy1 * WW + cx1];
        op[pix] = __float2bfloat16(v);
        lsum += v;
    }
    for (int off = 32; off > 0; off >>= 1) lsum += __shfl_down(lsum, off, 64);
    __shared__ float red[4];
    if ((threadIdx.x & 63) == 0) red[threadIdx.x >> 6] = lsum;
    __syncthreads();
    if (threadIdx.x == 0)
        p[plane] = (red[0] + red[1] + red[2] + red[3]) * (1.0f / (float)NPIX);
}

// Kernel 2: tiny MLP: h = relu(BN(p @ w1^T)); ca = sigmoid(h @ w2^T). One block.
__global__ void k_mlp(const float* __restrict__ p, const float* __restrict__ w1,
                      const float* __restrict__ g, const float* __restrict__ be,
                      const float* __restrict__ mu, const float* __restrict__ var,
                      const float* __restrict__ w2, float* __restrict__ ca) {
    __shared__ float sp[BB * CC];
    __shared__ float sh[BB * MID];
    int t = threadIdx.x;
    for (int i = t; i < BB * CC; i += 256) sp[i] = p[i];
    __syncthreads();
    for (int i = t; i < BB * MID; i += 256) {
        int b = i >> 6, m = i & (MID - 1);
        float acc = 0.f;
        for (int k = 0; k < CC; ++k) acc += sp[b * CC + k] * w1[m * CC + k];
        acc = (acc - mu[m]) * rsqrtf(var[m] + BN_EPS) * g[m] + be[m];
        sh[i] = fmaxf(acc, 0.f);
    }
    __syncthreads();
    for (int i = t; i < BB * CC; i += 256) {
        int b = i >> 8, ch = i & (CC - 1);
        float acc = 0.f;
        for (int k = 0; k < MID; ++k) acc += sh[b * MID + k] * w2[ch * MID + k];
        ca[i] = 1.f / (1.f + expf(-acc));
    }
}

// Kernel 3: per-pixel channel avg & max of fca = xr * ca.
__global__ void k_chanstat(const __hip_bfloat16* __restrict__ xr, const float* __restrict__ ca,
                           float* __restrict__ avg, float* __restrict__ mx) {
    int b = blockIdx.x >> 6;
    int pix = ((blockIdx.x & 63) << 8) + threadIdx.x;
    size_t base = (size_t)b * CC * NPIX + pix;
    const float* cab = ca + b * CC;
    float s = 0.f, m = -INFINITY;
    for (int ch = 0; ch < CC; ++ch) {
        float v = __bfloat162float(xr[base + (size_t)ch * NPIX]) * cab[ch];
        s += v;
        m = fmaxf(m, v);
    }
    avg[b * NPIX + pix] = s * (1.0f / (float)CC);
    mx[b * NPIX + pix] = m;
}

// Kernel 4: 7x7 conv (2 in-ch -> 1), pad 3, sigmoid -> sa.
__global__ void k_conv(const float* __restrict__ avg, const float* __restrict__ mx,
                       const float* __restrict__ w_sp, float* __restrict__ sa) {
    __shared__ float w[98];
    int t = threadIdx.x;
    if (t < 98) w[t] = w_sp[t];
    __syncthreads();
    int b = blockIdx.x >> 6;
    int pix = ((blockIdx.x & 63) << 8) + t;
    int yy = pix >> 7, xx = pix & (WW - 1);
    const float* a0 = avg + b * NPIX;
    const float* a1 = mx + b * NPIX;
    float acc = 0.f;
    for (int ky = 0; ky < 7; ++ky) {
        int ys = yy + ky - 3;
        if ((unsigned)ys >= HH) continue;
        for (int kx = 0; kx < 7; ++kx) {
            int xs = xx + kx - 3;
            if ((unsigned)xs >= WW) continue;
            acc += a0[ys * WW + xs] * w[ky * 7 + kx] + a1[ys * WW + xs] * w[49 + ky * 7 + kx];
        }
    }
    sa[b * NPIX + pix] = 1.f / (1.f + expf(-acc));
}

// Kernel 5 (tiled): inverse rotate fatt = xr*ca*sa by -angle, scale 1/4, accumulate.
// One block per (plane, 32x32 output tile). The tile's input footprint (affine map
// of the tile) is staged into LDS as the fused product bf16(xr)*sa with coalesced
// row-contiguous reads; bilinear gather then hits LDS only.
__global__ void k_invrot(const __hip_bfloat16* __restrict__ xr, const float* __restrict__ ca,
                         const float* __restrict__ sa, const float* __restrict__ angles,
                         int ai, int first, float* __restrict__ out) {
    __shared__ float lds[TROWS * TPITCH];

    int plane = blockIdx.x >> 4;            // b*CC + ch
    int tile  = blockIdx.x & 15;
    int b = plane >> 8;
    int ty = (tile >> 2) << 5;
    int tx = (tile & 3) << 5;

    float ang = angles[ai];
    float c = cosf(ang), s = -sinf(ang);    // inverse rotation grid
    float scale = ca[plane] * 0.25f;

    const __hip_bfloat16* xp = xr + (size_t)plane * NPIX;
    const float* sp = sa + b * NPIX;
    float* op = out + (size_t)plane * NPIX;

    // Input-space bbox of this output tile (affine -> extremes at corners).
    float ix00, iy00, ix10, iy10, ix01, iy01, ix11, iy11;
    rot_ixiy((float)tx,        (float)ty,        c, s, ix00, iy00);
    rot_ixiy((float)(tx + 31), (float)ty,        c, s, ix10, iy10);
    rot_ixiy((float)tx,        (float)(ty + 31), c, s, ix01, iy01);
    rot_ixiy((float)(tx + 31), (float)(ty + 31), c, s, ix11, iy11);
    float minix = fminf(fminf(ix00, ix10), fminf(ix01, ix11));
    float maxix = fmaxf(fmaxf(ix00, ix10), fmaxf(ix01, ix11));
    float miniy = fminf(fminf(iy00, iy10), fminf(iy01, iy11));
    float maxiy = fmaxf(fmaxf(iy00, iy10), fmaxf(iy01, iy11));
    int x_lo = max((int)floorf(minix) - 1, 0);
    int x_hi = min((int)floorf(maxix) + 2, WW - 1);
    int y_lo = max((int)floorf(miniy) - 1, 0);
    int y_hi = min((int)floorf(maxiy) + 2, HH - 1);
    x_hi = max(x_hi, x_lo);
    y_hi = max(y_hi, y_lo);
    int bw = x_hi - x_lo + 1;   // <= 48 for any rotation angle
    int bh = y_hi - y_lo + 1;

    // Stage product bf16(xr)*sa into LDS, coalesced along rows.
    int srow = threadIdx.x >> 6;        // 0..3
    int scol = threadIdx.x & 63;
    for (int r = srow; r < bh; r += 4) {
        if (scol < bw) {
            int g = (y_lo + r) * WW + (x_lo + scol);
            lds[r * TPITCH + scol] = __bfloat162float(xp[g]) * sp[g];
        }
    }
    __syncthreads();

    // Gather + write, 4 output pixels per thread.
    for (int k = 0; k < 4; ++k) {
        int p = threadIdx.x + (k << 8);
        int yy = ty + (p >> 5);
        int xx = tx + (p & 31);
        int x0, y0; float wx1, wy1;
        rot_coords(xx, yy, c, s, x0, y0, wx1, wy1);
        int x1 = x0 + 1, y1 = y0 + 1;
        float wx0 = 1.f - wx1, wy0 = 1.f - wy1;
        bool vx0 = (unsigned)x0 < WW, vx1 = (unsigned)x1 < WW;
        bool vy0 = (unsigned)y0 < HH, vy1 = (unsigned)y1 < HH;
        float w00 = (vx0 && vy0) ? wx0 * wy0 : 0.f;
        float w10 = (vx1 && vy0) ? wx1 * wy0 : 0.f;
        float w01 = (vx0 && vy1) ? wx0 * wy1 : 0.f;
        float w11 = (vx1 && vy1) ? wx1 * wy1 : 0.f;
        int lx0 = min(max(x0 - x_lo, 0), bw - 1);
        int lx1 = min(max(x1 - x_lo, 0), bw - 1);
        int ly0 = min(max(y0 - y_lo, 0), bh - 1);
        int ly1 = min(max(y1 - y_lo, 0), bh - 1);
        float v = w00 * lds[ly0 * TPITCH + lx0]
                + w10 * lds[ly0 * TPITCH + lx1]
                + w01 * lds[ly1 * TPITCH + lx0]
                + w11 * lds[ly1 * TPITCH + lx1];
        float o = v * scale;
        int oi = yy * WW + xx;
        if (first) op[oi] = o;
        else       op[oi] += o;
    }
}

extern "C" void kernel_launch(void* const* d_in, const int* in_sizes, int n_in,
                              void* d_out, int out_size, void* d_ws, size_t ws_size,
                              hipStream_t stream) {
    const float* x      = (const float*)d_in[0];
    const float* angles = (const float*)d_in[1];
    const float* w1     = (const float*)d_in[2];
    const float* gmm    = (const float*)d_in[3];
    const float* bet    = (const float*)d_in[4];
    const float* mu     = (const float*)d_in[5];
    const float* var    = (const float*)d_in[6];
    const float* w2     = (const float*)d_in[7];
    const float* wsp    = (const float*)d_in[8];
    float* out = (float*)d_out;

    char* ws = (char*)d_ws;
    __hip_bfloat16* xr = (__hip_bfloat16*)ws;                 // 64 MiB
    float* p   = (float*)(ws + (size_t)BB * CC * NPIX * 2);
    float* ca  = p + BB * CC;
    float* avg = ca + BB * CC;
    float* mx  = avg + BB * NPIX;
    float* sa  = mx + BB * NPIX;

    for (int ai = 0; ai < 4; ++ai) {
        k_rotate  <<<BB * CC, 256, 0, stream>>>(x, angles, ai, xr, p);
        k_mlp     <<<1, 256, 0, stream>>>(p, w1, gmm, bet, mu, var, w2, ca);
        k_chanstat<<<BB * 64, 256, 0, stream>>>(xr, ca, avg, mx);
        k_conv    <<<BB * 64, 256, 0, stream>>>(avg, mx, wsp, sa);
        k_invrot  <<<BB * CC * 16, 256, 0, stream>>>(xr, ca, sa, angles, ai, ai == 0, out);
    }
}

// Round 3
// 1637.302 us; speedup vs baseline: 1.6088x; 1.0408x over previous
//
#include <hip/hip_runtime.h>
#include <hip/hip_bf16.h>
#include <math.h>

#define BB   8
#define CC   256
#define HH   128
#define WW   128
#define MID  64
#define NPIX (HH * WW)          // 16384
#define BN_EPS 1e-5f

// LDS staging pitch/rows for 32x32-output-tile rotation kernels.
// Max input bbox span for a 31-px tile under any rotation: 31*sqrt(2)+3 < 48.
#define TPITCH 56
#define TROWS  56

__device__ __forceinline__ void rot_coords(int xx, int yy, float c, float s,
                                           int& x0, int& y0, float& wx1, float& wy1) {
    float X = -1.0f + (2.0f * (float)xx) / (float)(WW - 1);
    float Y = -1.0f + (2.0f * (float)yy) / (float)(HH - 1);
    float gx = c * X - s * Y;
    float gy = s * X + c * Y;
    float ix = (gx + 1.0f) * 0.5f * (float)(WW - 1);
    float iy = (gy + 1.0f) * 0.5f * (float)(HH - 1);
    float fx = floorf(ix), fy = floorf(iy);
    x0 = (int)fx; y0 = (int)fy;
    wx1 = ix - fx; wy1 = iy - fy;
}

__device__ __forceinline__ void rot_ixiy(float xx, float yy, float c, float s,
                                         float& ix, float& iy) {
    float X = -1.0f + (2.0f * xx) / (float)(WW - 1);
    float Y = -1.0f + (2.0f * yy) / (float)(HH - 1);
    float gx = c * X - s * Y;
    float gy = s * X + c * Y;
    ix = (gx + 1.0f) * 0.5f * (float)(WW - 1);
    iy = (gy + 1.0f) * 0.5f * (float)(HH - 1);
}

// Compute input-space bbox for a 32x32 output tile under rotation (c,s).
__device__ __forceinline__ void tile_bbox(int tx, int ty, float c, float s,
                                          int& x_lo, int& y_lo, int& bw, int& bh) {
    float ix00, iy00, ix10, iy10, ix01, iy01, ix11, iy11;
    rot_ixiy((float)tx,        (float)ty,        c, s, ix00, iy00);
    rot_ixiy((float)(tx + 31), (float)ty,        c, s, ix10, iy10);
    rot_ixiy((float)tx,        (float)(ty + 31), c, s, ix01, iy01);
    rot_ixiy((float)(tx + 31), (float)(ty + 31), c, s, ix11, iy11);
    float minix = fminf(fminf(ix00, ix10), fminf(ix01, ix11));
    float maxix = fmaxf(fmaxf(ix00, ix10), fmaxf(ix01, ix11));
    float miniy = fminf(fminf(iy00, iy10), fminf(iy01, iy11));
    float maxiy = fmaxf(fmaxf(iy00, iy10), fmaxf(iy01, iy11));
    x_lo = max((int)floorf(minix) - 1, 0);
    int x_hi = min((int)floorf(maxix) + 2, WW - 1);
    y_lo = max((int)floorf(miniy) - 1, 0);
    int y_hi = min((int)floorf(maxiy) + 2, HH - 1);
    x_hi = max(x_hi, x_lo);
    y_hi = max(y_hi, y_lo);
    bw = x_hi - x_lo + 1;   // <= 48
    bh = y_hi - y_lo + 1;
}

// Kernel 1 (tiled): rotate x by +angle into bf16 xr; per-tile partial sum -> p_part.
// One block per (plane, 32x32 tile). Input bbox staged in LDS, gather from LDS.
__global__ void k_rotate(const float* __restrict__ x, const float* __restrict__ angles,
                         int ai, __hip_bfloat16* __restrict__ xr, float* __restrict__ p_part) {
    __shared__ float lds[TROWS * TPITCH];
    __shared__ float red[4];

    int plane = blockIdx.x >> 4;
    int tile  = blockIdx.x & 15;
    int ty = (tile >> 2) << 5;
    int tx = (tile & 3) << 5;

    float ang = angles[ai];
    float c = cosf(ang), s = sinf(ang);

    const float* img = x + (size_t)plane * NPIX;
    __hip_bfloat16* op = xr + (size_t)plane * NPIX;

    int x_lo, y_lo, bw, bh;
    tile_bbox(tx, ty, c, s, x_lo, y_lo, bw, bh);

    int srow = threadIdx.x >> 6;
    int scol = threadIdx.x & 63;
    for (int r = srow; r < bh; r += 4) {
        if (scol < bw)
            lds[r * TPITCH + scol] = img[(y_lo + r) * WW + (x_lo + scol)];
    }
    __syncthreads();

    float lsum = 0.0f;
    for (int k = 0; k < 4; ++k) {
        int p = threadIdx.x + (k << 8);
        int yy = ty + (p >> 5);
        int xx = tx + (p & 31);
        int x0, y0; float wx1, wy1;
        rot_coords(xx, yy, c, s, x0, y0, wx1, wy1);
        int x1 = x0 + 1, y1 = y0 + 1;
        float wx0 = 1.f - wx1, wy0 = 1.f - wy1;
        bool vx0 = (unsigned)x0 < WW, vx1 = (unsigned)x1 < WW;
        bool vy0 = (unsigned)y0 < HH, vy1 = (unsigned)y1 < HH;
        float w00 = (vx0 && vy0) ? wx0 * wy0 : 0.f;
        float w10 = (vx1 && vy0) ? wx1 * wy0 : 0.f;
        float w01 = (vx0 && vy1) ? wx0 * wy1 : 0.f;
        float w11 = (vx1 && vy1) ? wx1 * wy1 : 0.f;
        int lx0 = min(max(x0 - x_lo, 0), bw - 1);
        int lx1 = min(max(x1 - x_lo, 0), bw - 1);
        int ly0 = min(max(y0 - y_lo, 0), bh - 1);
        int ly1 = min(max(y1 - y_lo, 0), bh - 1);
        float v = w00 * lds[ly0 * TPITCH + lx0]
                + w10 * lds[ly0 * TPITCH + lx1]
                + w01 * lds[ly1 * TPITCH + lx0]
                + w11 * lds[ly1 * TPITCH + lx1];
        op[yy * WW + xx] = __float2bfloat16(v);
        lsum += v;
    }
    for (int off = 32; off > 0; off >>= 1) lsum += __shfl_down(lsum, off, 64);
    if ((threadIdx.x & 63) == 0) red[threadIdx.x >> 6] = lsum;
    __syncthreads();
    if (threadIdx.x == 0)
        p_part[blockIdx.x] = red[0] + red[1] + red[2] + red[3];
}

// Kernel 2: reduce p_part, tiny MLP: h = relu(BN(p @ w1^T)); ca = sigmoid(h @ w2^T).
__global__ void k_mlp(const float* __restrict__ p_part, const float* __restrict__ w1,
                      const float* __restrict__ g, const float* __restrict__ be,
                      const float* __restrict__ mu, const float* __restrict__ var,
                      const float* __restrict__ w2, float* __restrict__ ca) {
    __shared__ float sp[BB * CC];
    __shared__ float sh[BB * MID];
    int t = threadIdx.x;
    for (int i = t; i < BB * CC; i += 256) {
        float acc = 0.f;
        for (int k = 0; k < 16; ++k) acc += p_part[i * 16 + k];
        sp[i] = acc * (1.0f / (float)NPIX);
    }
    __syncthreads();
    for (int i = t; i < BB * MID; i += 256) {
        int b = i >> 6, m = i & (MID - 1);
        float acc = 0.f;
        for (int k = 0; k < CC; ++k) acc += sp[b * CC + k] * w1[m * CC + k];
        acc = (acc - mu[m]) * rsqrtf(var[m] + BN_EPS) * g[m] + be[m];
        sh[i] = fmaxf(acc, 0.f);
    }
    __syncthreads();
    for (int i = t; i < BB * CC; i += 256) {
        int b = i >> 8, ch = i & (CC - 1);
        float acc = 0.f;
        for (int k = 0; k < MID; ++k) acc += sh[b * MID + k] * w2[ch * MID + k];
        ca[i] = 1.f / (1.f + expf(-acc));
    }
}

// Kernel 3: per-pixel channel avg & max of fca = xr * ca. 2 pixels/thread (packed bf16x2).
__global__ void k_chanstat(const __hip_bfloat16* __restrict__ xr, const float* __restrict__ ca,
                           float* __restrict__ avg, float* __restrict__ mx) {
    int b = blockIdx.x >> 5;
    int pp = ((blockIdx.x & 31) << 8) + threadIdx.x;   // pixel-pair index, 0..8191
    const unsigned* xp = (const unsigned*)(xr + (size_t)b * CC * NPIX) + pp;
    const float* cab = ca + b * CC;
    float s0 = 0.f, s1 = 0.f, m0 = -INFINITY, m1 = -INFINITY;
    for (int ch = 0; ch < CC; ++ch) {
        unsigned u = xp[(size_t)ch * (NPIX / 2)];
        float v0 = __uint_as_float(u << 16);
        float v1 = __uint_as_float(u & 0xffff0000u);
        float cc = cab[ch];
        v0 *= cc; v1 *= cc;
        s0 += v0; s1 += v1;
        m0 = fmaxf(m0, v0); m1 = fmaxf(m1, v1);
    }
    float2* ap = (float2*)(avg + b * NPIX);
    float2* mp = (float2*)(mx + b * NPIX);
    ap[pp] = make_float2(s0 * (1.0f / (float)CC), s1 * (1.0f / (float)CC));
    mp[pp] = make_float2(m0, m1);
}

// Kernel 4: 7x7 conv (2 in-ch -> 1), pad 3, sigmoid -> sa.
__global__ void k_conv(const float* __restrict__ avg, const float* __restrict__ mx,
                       const float* __restrict__ w_sp, float* __restrict__ sa) {
    __shared__ float w[98];
    int t = threadIdx.x;
    if (t < 98) w[t] = w_sp[t];
    __syncthreads();
    int b = blockIdx.x >> 6;
    int pix = ((blockIdx.x & 63) << 8) + t;
    int yy = pix >> 7, xx = pix & (WW - 1);
    const float* a0 = avg + b * NPIX;
    const float* a1 = mx + b * NPIX;
    float acc = 0.f;
    for (int ky = 0; ky < 7; ++ky) {
        int ys = yy + ky - 3;
        if ((unsigned)ys >= HH) continue;
        for (int kx = 0; kx < 7; ++kx) {
            int xs = xx + kx - 3;
            if ((unsigned)xs >= WW) continue;
            acc += a0[ys * WW + xs] * w[ky * 7 + kx] + a1[ys * WW + xs] * w[49 + ky * 7 + kx];
        }
    }
    sa[b * NPIX + pix] = 1.f / (1.f + expf(-acc));
}

// Kernel 5 (tiled): inverse rotate fatt = xr*ca*sa by -angle, scale 1/4, accumulate.
__global__ void k_invrot(const __hip_bfloat16* __restrict__ xr, const float* __restrict__ ca,
                         const float* __restrict__ sa, const float* __restrict__ angles,
                         int ai, int first, float* __restrict__ out) {
    __shared__ float lds[TROWS * TPITCH];

    int plane = blockIdx.x >> 4;
    int tile  = blockIdx.x & 15;
    int b = plane >> 8;
    int ty = (tile >> 2) << 5;
    int tx = (tile & 3) << 5;

    float ang = angles[ai];
    float c = cosf(ang), s = -sinf(ang);
    float scale = ca[plane] * 0.25f;

    const __hip_bfloat16* xp = xr + (size_t)plane * NPIX;
    const float* sp = sa + b * NPIX;
    float* op = out + (size_t)plane * NPIX;

    int x_lo, y_lo, bw, bh;
    tile_bbox(tx, ty, c, s, x_lo, y_lo, bw, bh);

    int srow = threadIdx.x >> 6;
    int scol = threadIdx.x & 63;
    for (int r = srow; r < bh; r += 4) {
        if (scol < bw) {
            int g = (y_lo + r) * WW + (x_lo + scol);
            lds[r * TPITCH + scol] = __bfloat162float(xp[g]) * sp[g];
        }
    }
    __syncthreads();

    for (int k = 0; k < 4; ++k) {
        int p = threadIdx.x + (k << 8);
        int yy = ty + (p >> 5);
        int xx = tx + (p & 31);
        int x0, y0; float wx1, wy1;
        rot_coords(xx, yy, c, s, x0, y0, wx1, wy1);
        int x1 = x0 + 1, y1 = y0 + 1;
        float wx0 = 1.f - wx1, wy0 = 1.f - wy1;
        bool vx0 = (unsigned)x0 < WW, vx1 = (unsigned)x1 < WW;
        bool vy0 = (unsigned)y0 < HH, vy1 = (unsigned)y1 < HH;
        float w00 = (vx0 && vy0) ? wx0 * wy0 : 0.f;
        float w10 = (vx1 && vy0) ? wx1 * wy0 : 0.f;
        float w01 = (vx0 && vy1) ? wx0 * wy1 : 0.f;
        float w11 = (vx1 && vy1) ? wx1 * wy1 : 0.f;
        int lx0 = min(max(x0 - x_lo, 0), bw - 1);
        int lx1 = min(max(x1 - x_lo, 0), bw - 1);
        int ly0 = min(max(y0 - y_lo, 0), bh - 1);
        int ly1 = min(max(y1 - y_lo, 0), bh - 1);
        float v = w00 * lds[ly0 * TPITCH + lx0]
                + w10 * lds[ly0 * TPITCH + lx1]
                + w01 * lds[ly1 * TPITCH + lx0]
                + w11 * lds[ly1 * TPITCH + lx1];
        float o = v * scale;
        int oi = yy * WW + xx;
        if (first) op[oi] = o;
        else       op[oi] += o;
    }
}

extern "C" void kernel_launch(void* const* d_in, const int* in_sizes, int n_in,
                              void* d_out, int out_size, void* d_ws, size_t ws_size,
                              hipStream_t stream) {
    const float* x      = (const float*)d_in[0];
    const float* angles = (const float*)d_in[1];
    const float* w1     = (const float*)d_in[2];
    const float* gmm    = (const float*)d_in[3];
    const float* bet    = (const float*)d_in[4];
    const float* mu     = (const float*)d_in[5];
    const float* var    = (const float*)d_in[6];
    const float* w2     = (const float*)d_in[7];
    const float* wsp    = (const float*)d_in[8];
    float* out = (float*)d_out;

    char* ws = (char*)d_ws;
    __hip_bfloat16* xr = (__hip_bfloat16*)ws;                   // 64 MiB
    float* p_part = (float*)(ws + (size_t)BB * CC * NPIX * 2);  // 2048*16 floats
    float* ca  = p_part + BB * CC * 16;
    float* avg = ca + BB * CC;
    float* mx  = avg + BB * NPIX;
    float* sa  = mx + BB * NPIX;

    for (int ai = 0; ai < 4; ++ai) {
        k_rotate  <<<BB * CC * 16, 256, 0, stream>>>(x, angles, ai, xr, p_part);
        k_mlp     <<<1, 256, 0, stream>>>(p_part, w1, gmm, bet, mu, var, w2, ca);
        k_chanstat<<<BB * 32, 256, 0, stream>>>(xr, ca, avg, mx);
        k_conv    <<<BB * 64, 256, 0, stream>>>(avg, mx, wsp, sa);
        k_invrot  <<<BB * CC * 16, 256, 0, stream>>>(xr, ca, sa, angles, ai, ai == 0, out);
    }
}